// Round 1
// baseline (377.298 us; speedup 1.0000x reference)
//
#include <hip/hip_runtime.h>
#include <stdint.h>

typedef unsigned short u16;
typedef __attribute__((ext_vector_type(8))) short bf8;   // 8 x bf16 (4 VGPRs)
typedef __attribute__((ext_vector_type(4))) float f4;    // 4 x f32

#define NTOK 2048
#define MTOK 4096    // 2*2048
#define DIM  1024
#define E3   3072

__device__ __forceinline__ u16 f2bf(float f) {
    uint32_t u = __float_as_uint(f);
    u += 0x7FFF + ((u >> 16) & 1);   // RNE
    return (u16)(u >> 16);
}
__device__ __forceinline__ float bf2f(u16 v) {
    return __uint_as_float(((uint32_t)v) << 16);
}

__device__ __forceinline__ void gld_lds16(const u16* g, u16* l) {
    __builtin_amdgcn_global_load_lds(
        (const __attribute__((address_space(1))) void*)g,
        (__attribute__((address_space(3))) void*)l, 16, 0, 0);
}

// ---------------- fp32 -> bf16 conversion ----------------
struct alignas(8) US4 { u16 a, b, c, d; };

__global__ void cvt_kernel(const float* __restrict__ in, u16* __restrict__ out, int n4) {
    int i = blockIdx.x * blockDim.x + threadIdx.x;
    if (i < n4) {
        float4 v = ((const float4*)in)[i];
        US4 o; o.a = f2bf(v.x); o.b = f2bf(v.y); o.c = f2bf(v.z); o.d = f2bf(v.w);
        ((US4*)out)[i] = o;
    }
}

// ---------------- GEMM1: qkv projection ----------------
// A[4096][1024] bf16, W[3072][1024] bf16 (B^T layout); writes Q,K,V [b][h][n][64] bf16
__global__ __launch_bounds__(256)
void gemm_qkv(const u16* __restrict__ A, const u16* __restrict__ W,
              u16* __restrict__ Qo, u16* __restrict__ Ko, u16* __restrict__ Vo)
{
    __shared__ __align__(16) u16 lA[128 * 64];
    __shared__ __align__(16) u16 lB[128 * 64];
    const int tid = threadIdx.x;
    const int lane = tid & 63, wid = tid >> 6;
    const int g = lane >> 4, c = lane & 15;
    const int m0 = blockIdx.y * 128, n0 = blockIdx.x * 128;
    const int wr = wid >> 1, wc = wid & 1;

    f4 acc[4][4];
#pragma unroll
    for (int i = 0; i < 4; ++i)
#pragma unroll
        for (int j = 0; j < 4; ++j) { acc[i][j][0] = 0.f; acc[i][j][1] = 0.f; acc[i][j][2] = 0.f; acc[i][j][3] = 0.f; }

    for (int k0 = 0; k0 < 1024; k0 += 64) {
        __syncthreads();
#pragma unroll
        for (int i = 0; i < 4; ++i) {
            int chunk = i * 256 + tid;
            int row = chunk >> 3, cc = chunk & 7;
            int gc = cc ^ (row & 7);                   // swizzled global source
            gld_lds16(A + (m0 + row) * 1024 + k0 + gc * 8, lA + (i * 256 + wid * 64) * 8);
            gld_lds16(W + (n0 + row) * 1024 + k0 + gc * 8, lB + (i * 256 + wid * 64) * 8);
        }
        __syncthreads();
#pragma unroll
        for (int kk = 0; kk < 2; ++kk) {
            bf8 af[4], bfr[4];
#pragma unroll
            for (int mi = 0; mi < 4; ++mi) {
                int row = wr * 64 + mi * 16 + c;
                af[mi] = *(const bf8*)&lA[row * 64 + ((kk * 4 + g) ^ (row & 7)) * 8];
            }
#pragma unroll
            for (int ni = 0; ni < 4; ++ni) {
                int row = wc * 64 + ni * 16 + c;
                bfr[ni] = *(const bf8*)&lB[row * 64 + ((kk * 4 + g) ^ (row & 7)) * 8];
            }
#pragma unroll
            for (int mi = 0; mi < 4; ++mi)
#pragma unroll
                for (int ni = 0; ni < 4; ++ni)
                    acc[mi][ni] = __builtin_amdgcn_mfma_f32_16x16x32_bf16(af[mi], bfr[ni], acc[mi][ni], 0, 0, 0);
        }
    }
    // epilogue: split q/k/v, permute to [b][h][n][64], scale q by 1/8
#pragma unroll
    for (int mi = 0; mi < 4; ++mi) {
        int tok0 = m0 + wr * 64 + mi * 16 + g * 4;
#pragma unroll
        for (int ni = 0; ni < 4; ++ni) {
            int e = n0 + wc * 64 + ni * 16 + c;
            int part = e >> 10;
            int eh = e & 1023;
            int h = eh >> 6, d = eh & 63;
            u16* dst = (part == 0) ? Qo : ((part == 1) ? Ko : Vo);
            float scale = (part == 0) ? 0.125f : 1.0f;
#pragma unroll
            for (int r = 0; r < 4; ++r) {
                int tok = tok0 + r;
                int b = tok >> 11, n = tok & 2047;
                dst[((b * 16 + h) * 2048 + n) * 64 + d] = f2bf(acc[mi][ni][r] * scale);
            }
        }
    }
}

// ---------------- vmean: per (b,h) mean of V rows ----------------
__global__ void vmean_kernel(const u16* __restrict__ V, float* __restrict__ vmean) {
    int bh = blockIdx.x;
    int tid = threadIdx.x;
    int d = tid & 63, ch = tid >> 6;
    const u16* Vb = V + bh * 2048 * 64;
    float s = 0.f;
    for (int kv = ch * 512; kv < ch * 512 + 512; ++kv) s += bf2f(Vb[kv * 64 + d]);
    __shared__ float red[256];
    red[tid] = s;
    __syncthreads();
    if (ch == 0)
        vmean[bh * 64 + d] = (red[d] + red[64 + d] + red[128 + d] + red[192 + d]) * (1.0f / 2048.0f);
}

// ---------------- flash attention ----------------
// grid: x = q-tile (32), y = bh (32). 4 waves, 16 q-rows each, KV tile = 64.
__global__ __launch_bounds__(256)
void attn_kernel(const u16* __restrict__ Q, const u16* __restrict__ K, const u16* __restrict__ V,
                 const int* __restrict__ mask, const float* __restrict__ vmean,
                 u16* __restrict__ O)
{
    __shared__ __align__(16) u16 lK[64 * 64];
    __shared__ __align__(16) u16 lVt[64 * 64];
    __shared__ __align__(16) u16 lP[4][16 * 64];
    __shared__ int lmask[2048];
    const int tid = threadIdx.x;
    const int lane = tid & 63, wid = tid >> 6;
    const int g = lane >> 4, c = lane & 15;
    const int bh = blockIdx.y, b = bh >> 4, h = bh & 15;
    const int qt = blockIdx.x;
    const u16* Qb = Q + bh * 2048 * 64;
    const u16* Kb = K + bh * 2048 * 64;
    const u16* Vb = V + bh * 2048 * 64;

    for (int i = tid; i < 2048; i += 256) lmask[i] = mask[b * 2048 + i];

    const int qrow = qt * 64 + wid * 16 + c;
    bf8 qf0 = *(const bf8*)&Qb[qrow * 64 + g * 8];
    bf8 qf1 = *(const bf8*)&Qb[qrow * 64 + 32 + g * 8];

    f4 oacc[4];
#pragma unroll
    for (int i = 0; i < 4; ++i) { oacc[i][0] = 0.f; oacc[i][1] = 0.f; oacc[i][2] = 0.f; oacc[i][3] = 0.f; }
    float mrun[4] = { -1e30f, -1e30f, -1e30f, -1e30f };
    float lrun[4] = { 0.f, 0.f, 0.f, 0.f };

    __syncthreads();   // mask staged

    for (int t = 0; t < 32; ++t) {
        __syncthreads();   // previous tile's LDS reads done
        // stage K tile (swizzled source, linear LDS dest)
#pragma unroll
        for (int i = 0; i < 2; ++i) {
            int chunk = i * 256 + tid;
            int row = chunk >> 3, cc = chunk & 7;
            int gc = cc ^ (row & 7);
            gld_lds16(Kb + (t * 64 + row) * 64 + gc * 8, lK + (i * 256 + wid * 64) * 8);
        }
        // stage V transposed (reg-staged scalar writes, kv-chunk swizzle)
#pragma unroll
        for (int i = 0; i < 2; ++i) {
            int kvl = (tid >> 3) + i * 32;
            int d0 = (tid & 7) * 8;
            bf8 v = *(const bf8*)&Vb[(t * 64 + kvl) * 64 + d0];
#pragma unroll
            for (int j = 0; j < 8; ++j) {
                int d = d0 + j;
                int sc = (((kvl >> 3) ^ (d & 7)) << 3) | (kvl & 7);
                lVt[d * 64 + sc] = (u16)v[j];
            }
        }
        __syncthreads();

        // S = Q K^T  (scale already folded into Q)
        f4 s[4];
#pragma unroll
        for (int nf = 0; nf < 4; ++nf) {
            int row = nf * 16 + c;
            bf8 k0 = *(const bf8*)&lK[row * 64 + ((0 * 4 + g) ^ (row & 7)) * 8];
            bf8 k1 = *(const bf8*)&lK[row * 64 + ((1 * 4 + g) ^ (row & 7)) * 8];
            f4 z; z[0] = 0.f; z[1] = 0.f; z[2] = 0.f; z[3] = 0.f;
            z = __builtin_amdgcn_mfma_f32_16x16x32_bf16(qf0, k0, z, 0, 0, 0);
            z = __builtin_amdgcn_mfma_f32_16x16x32_bf16(qf1, k1, z, 0, 0, 0);
            if (lmask[t * 64 + row] == 0) { z[0] = -1e30f; z[1] = -1e30f; z[2] = -1e30f; z[3] = -1e30f; }
            s[nf] = z;
        }
        // online softmax per row r (rows g*4+r, columns across 16 lanes of group g)
        float alpha[4];
#pragma unroll
        for (int r = 0; r < 4; ++r) {
            float tm = fmaxf(fmaxf(s[0][r], s[1][r]), fmaxf(s[2][r], s[3][r]));
#pragma unroll
            for (int off = 8; off; off >>= 1) tm = fmaxf(tm, __shfl_xor(tm, off));
            float mnew = fmaxf(mrun[r], tm);
            alpha[r] = __expf(mrun[r] - mnew);
            mrun[r] = mnew;
            float ts = 0.f;
#pragma unroll
            for (int nf = 0; nf < 4; ++nf) {
                float p = __expf(s[nf][r] - mnew);
                s[nf][r] = p;
                ts += p;
            }
#pragma unroll
            for (int off = 8; off; off >>= 1) ts += __shfl_xor(ts, off);
            lrun[r] = lrun[r] * alpha[r] + ts;
#pragma unroll
            for (int df = 0; df < 4; ++df) oacc[df][r] *= alpha[r];
        }
        // P -> per-wave LDS (bf16, swizzled), re-fragment as MFMA A operand
        u16* Pw = lP[wid];
#pragma unroll
        for (int nf = 0; nf < 4; ++nf) {
#pragma unroll
            for (int r = 0; r < 4; ++r) {
                int prow = g * 4 + r;
                int chunkp = (nf * 16 + c) >> 3;
                int sc = ((chunkp ^ (prow & 7)) << 3) | (c & 7);
                Pw[prow * 64 + sc] = f2bf(s[nf][r]);
            }
        }
        // O += P V
#pragma unroll
        for (int kk = 0; kk < 2; ++kk) {
            bf8 pf = *(const bf8*)&Pw[c * 64 + ((kk * 4 + g) ^ (c & 7)) * 8];
#pragma unroll
            for (int df = 0; df < 4; ++df) {
                int vrow = df * 16 + c;
                bf8 vf = *(const bf8*)&lVt[vrow * 64 + ((kk * 4 + g) ^ (vrow & 7)) * 8];
                oacc[df] = __builtin_amdgcn_mfma_f32_16x16x32_bf16(pf, vf, oacc[df], 0, 0, 0);
            }
        }
    }
    // epilogue: divide by l; masked-out query rows get uniform mean of V
#pragma unroll
    for (int r = 0; r < 4; ++r) {
        int qr = qt * 64 + wid * 16 + g * 4 + r;
        int mi = lmask[qr];
        float inv = 1.0f / lrun[r];
#pragma unroll
        for (int df = 0; df < 4; ++df) {
            int d = df * 16 + c;
            float val = mi ? oacc[df][r] * inv : vmean[bh * 64 + d];
            O[((b * 2048 + qr) * 16 + h) * 64 + d] = f2bf(val);
        }
    }
}

// ---------------- GEMM2: output projection ----------------
// A = attention out [4096][1024] bf16, W = w_out bf16 [1024][1024] (B^T); out fp32
__global__ __launch_bounds__(256)
void gemm_out(const u16* __restrict__ A, const u16* __restrict__ W, float* __restrict__ out)
{
    __shared__ __align__(16) u16 lA[128 * 64];
    __shared__ __align__(16) u16 lB[128 * 64];
    const int tid = threadIdx.x;
    const int lane = tid & 63, wid = tid >> 6;
    const int g = lane >> 4, c = lane & 15;
    const int m0 = blockIdx.y * 128, n0 = blockIdx.x * 128;
    const int wr = wid >> 1, wc = wid & 1;

    f4 acc[4][4];
#pragma unroll
    for (int i = 0; i < 4; ++i)
#pragma unroll
        for (int j = 0; j < 4; ++j) { acc[i][j][0] = 0.f; acc[i][j][1] = 0.f; acc[i][j][2] = 0.f; acc[i][j][3] = 0.f; }

    for (int k0 = 0; k0 < 1024; k0 += 64) {
        __syncthreads();
#pragma unroll
        for (int i = 0; i < 4; ++i) {
            int chunk = i * 256 + tid;
            int row = chunk >> 3, cc = chunk & 7;
            int gc = cc ^ (row & 7);
            gld_lds16(A + (m0 + row) * 1024 + k0 + gc * 8, lA + (i * 256 + wid * 64) * 8);
            gld_lds16(W + (n0 + row) * 1024 + k0 + gc * 8, lB + (i * 256 + wid * 64) * 8);
        }
        __syncthreads();
#pragma unroll
        for (int kk = 0; kk < 2; ++kk) {
            bf8 af[4], bfr[4];
#pragma unroll
            for (int mi = 0; mi < 4; ++mi) {
                int row = wr * 64 + mi * 16 + c;
                af[mi] = *(const bf8*)&lA[row * 64 + ((kk * 4 + g) ^ (row & 7)) * 8];
            }
#pragma unroll
            for (int ni = 0; ni < 4; ++ni) {
                int row = wc * 64 + ni * 16 + c;
                bfr[ni] = *(const bf8*)&lB[row * 64 + ((kk * 4 + g) ^ (row & 7)) * 8];
            }
#pragma unroll
            for (int mi = 0; mi < 4; ++mi)
#pragma unroll
                for (int ni = 0; ni < 4; ++ni)
                    acc[mi][ni] = __builtin_amdgcn_mfma_f32_16x16x32_bf16(af[mi], bfr[ni], acc[mi][ni], 0, 0, 0);
        }
    }
#pragma unroll
    for (int mi = 0; mi < 4; ++mi) {
        int row0 = m0 + wr * 64 + mi * 16 + g * 4;
#pragma unroll
        for (int ni = 0; ni < 4; ++ni) {
            int col = n0 + wc * 64 + ni * 16 + c;
#pragma unroll
            for (int r = 0; r < 4; ++r)
                out[(row0 + r) * 1024 + col] = acc[mi][ni][r];
        }
    }
}

extern "C" void kernel_launch(void* const* d_in, const int* in_sizes, int n_in,
                              void* d_out, int out_size, void* d_ws, size_t ws_size,
                              hipStream_t stream) {
    const float* x    = (const float*)d_in[0];
    const int*   mask = (const int*)d_in[1];
    const float* wqkv = (const float*)d_in[2];
    const float* wout = (const float*)d_in[3];
    float* out = (float*)d_out;

    u16* ws = (u16*)d_ws;
    u16* xbf    = ws;                       // 4096*1024   (reused as attention output)
    u16* wqkvbf = xbf + 4096 * 1024;        // 3072*1024
    u16* woutbf = wqkvbf + 3072 * 1024;     // 1024*1024
    u16* qb     = woutbf + 1024 * 1024;     // 2*16*2048*64
    u16* kb     = qb + 2 * 16 * 2048 * 64;
    u16* vb     = kb + 2 * 16 * 2048 * 64;
    float* vmean = (float*)(vb + 2 * 16 * 2048 * 64);   // 32*64 floats
    u16* ob = xbf;                          // alias: x-bf16 dead after gemm_qkv

    cvt_kernel<<<4096, 256, 0, stream>>>(x, xbf, 4096 * 1024 / 4);
    cvt_kernel<<<3072, 256, 0, stream>>>(wqkv, wqkvbf, 3072 * 1024 / 4);
    cvt_kernel<<<1024, 256, 0, stream>>>(wout, woutbf, 1024 * 1024 / 4);
    gemm_qkv<<<dim3(24, 32), 256, 0, stream>>>(xbf, wqkvbf, qb, kb, vb);
    vmean_kernel<<<32, 256, 0, stream>>>(vb, vmean);
    attn_kernel<<<dim3(32, 32), 256, 0, stream>>>(qb, kb, vb, mask, vmean, ob);
    gemm_out<<<dim3(8, 32), 256, 0, stream>>>(ob, woutbf, out);
}

// Round 2
// 150.412 us; speedup vs baseline: 2.5084x; 2.5084x over previous
//
#include <hip/hip_runtime.h>
#include <stdint.h>

typedef unsigned short u16;
typedef uint32_t u32;
typedef __attribute__((ext_vector_type(8))) short bf8;    // 8 x bf16
typedef __attribute__((ext_vector_type(4))) float f4;     // 4 x f32
typedef __attribute__((ext_vector_type(16))) float f16f;  // 16 x f32
typedef __attribute__((ext_vector_type(4))) unsigned short us4;

__device__ __forceinline__ u16 f2bf(float f) {
    uint32_t u = __float_as_uint(f);
    u += 0x7FFF + ((u >> 16) & 1);   // RNE
    return (u16)(u >> 16);
}
__device__ __forceinline__ float bf2f(u16 v) {
    return __uint_as_float(((uint32_t)v) << 16);
}
__device__ __forceinline__ void gld_lds16(const u16* g, u16* l) {
    __builtin_amdgcn_global_load_lds(
        (const __attribute__((address_space(1))) void*)g,
        (__attribute__((address_space(3))) void*)l, 16, 0, 0);
}
__device__ __forceinline__ f16f mfma32(bf8 a, bf8 b, f16f c) {
    return __builtin_amdgcn_mfma_f32_32x32x16_bf16(a, b, c, 0, 0, 0);
}
__device__ __forceinline__ u32 cvtpk(float lo, float hi) {
    u32 r; asm("v_cvt_pk_bf16_f32 %0, %1, %2" : "=v"(r) : "v"(lo), "v"(hi)); return r;
}
__device__ __forceinline__ void plswap(u32& a, u32& b) {
    asm("v_permlane32_swap_b32 %0, %1" : "+v"(a), "+v"(b));
}

// ---------------- fp32 -> bf16 conversion ----------------
struct alignas(8) US4 { u16 a, b, c, d; };

__global__ void cvt_kernel(const float* __restrict__ in, u16* __restrict__ out, int n4) {
    int i = blockIdx.x * blockDim.x + threadIdx.x;
    if (i < n4) {
        float4 v = ((const float4*)in)[i];
        US4 o; o.a = f2bf(v.x); o.b = f2bf(v.y); o.c = f2bf(v.z); o.d = f2bf(v.w);
        ((US4*)out)[i] = o;
    }
}

// ---------------- GEMM1: qkv projection ----------------
// A[4096][1024] bf16, W[3072][1024] bf16 (B^T); writes Q,K [b][h][n][64], V^T [b][h][64][n]
__global__ __launch_bounds__(256)
void gemm_qkv(const u16* __restrict__ A, const u16* __restrict__ W,
              u16* __restrict__ Qo, u16* __restrict__ Ko, u16* __restrict__ Vo)
{
    __shared__ __align__(16) u16 lsmem[2 * 128 * 64];
    u16* lA = lsmem;
    u16* lB = lsmem + 128 * 64;
    const int tid = threadIdx.x;
    const int lane = tid & 63, wid = tid >> 6;
    const int g = lane >> 4, c = lane & 15;
    const int m0 = blockIdx.y * 128, n0 = blockIdx.x * 128;
    const int wr = wid >> 1, wc = wid & 1;

    f4 acc[4][4];
#pragma unroll
    for (int i = 0; i < 4; ++i)
#pragma unroll
        for (int j = 0; j < 4; ++j) { acc[i][j][0] = 0.f; acc[i][j][1] = 0.f; acc[i][j][2] = 0.f; acc[i][j][3] = 0.f; }

    for (int k0 = 0; k0 < 1024; k0 += 64) {
        __syncthreads();
#pragma unroll
        for (int i = 0; i < 4; ++i) {
            int chunk = i * 256 + tid;
            int row = chunk >> 3, cc = chunk & 7;
            int gc = cc ^ (row & 7);
            gld_lds16(A + (m0 + row) * 1024 + k0 + gc * 8, lA + (i * 256 + wid * 64) * 8);
            gld_lds16(W + (n0 + row) * 1024 + k0 + gc * 8, lB + (i * 256 + wid * 64) * 8);
        }
        __syncthreads();
#pragma unroll
        for (int kk = 0; kk < 2; ++kk) {
            bf8 af[4], bfr[4];
#pragma unroll
            for (int mi = 0; mi < 4; ++mi) {
                int row = wr * 64 + mi * 16 + c;
                af[mi] = *(const bf8*)&lA[row * 64 + ((kk * 4 + g) ^ (row & 7)) * 8];
            }
#pragma unroll
            for (int ni = 0; ni < 4; ++ni) {
                int row = wc * 64 + ni * 16 + c;
                bfr[ni] = *(const bf8*)&lB[row * 64 + ((kk * 4 + g) ^ (row & 7)) * 8];
            }
#pragma unroll
            for (int mi = 0; mi < 4; ++mi)
#pragma unroll
                for (int ni = 0; ni < 4; ++ni)
                    acc[mi][ni] = __builtin_amdgcn_mfma_f32_16x16x32_bf16(af[mi], bfr[ni], acc[mi][ni], 0, 0, 0);
        }
    }

    // ---- epilogue: per-wave 64x64 LDS transpose, coalesced 16B stores ----
    __syncthreads();                       // all waves done reading lA/lB
    u16* eb = lsmem + wid * 4096;          // 64x64 u16 per wave
    const int e0 = n0 + wc * 64;
    const int part = e0 >> 10;             // 0=Q 1=K 2=V
    const int hh = (e0 & 1023) >> 6;
    const float scale = (part == 0) ? 0.125f : 1.0f;

    if (part < 2) {
        // LDS tile [tokL][d], token-chunk-XOR swizzle on d-chunks
#pragma unroll
        for (int mi = 0; mi < 4; ++mi)
#pragma unroll
            for (int ni = 0; ni < 4; ++ni) {
                int colL = ni * 16 + c;
#pragma unroll
                for (int r = 0; r < 4; ++r) {
                    int tokL = mi * 16 + g * 4 + r;
                    int chk = ((colL >> 3) ^ (tokL & 7));
                    eb[tokL * 64 + chk * 8 + (colL & 7)] = f2bf(acc[mi][ni][r] * scale);
                }
            }
        u16* dst0 = (part == 0) ? Qo : Ko;
#pragma unroll
        for (int i = 0; i < 8; ++i) {
            int row = i * 8 + (lane >> 3);
            int ch = lane & 7;
            bf8 v = *(const bf8*)&eb[row * 64 + ((ch ^ (row & 7)) << 3)];
            int tok = m0 + wr * 64 + row;
            int bb = tok >> 11, nn = tok & 2047;
            *(bf8*)&dst0[((bb * 16 + hh) * 2048 + nn) * 64 + ch * 8] = v;
        }
    } else {
        // V: LDS tile [d][tokL] (transposed), d-XOR swizzle on tok-chunks
#pragma unroll
        for (int mi = 0; mi < 4; ++mi)
#pragma unroll
            for (int ni = 0; ni < 4; ++ni) {
                int dL = ni * 16 + c;
                int tokL0 = mi * 16 + g * 4;
                int tchk = ((tokL0 >> 3) ^ (dL & 7));
                us4 w;
                w[0] = f2bf(acc[mi][ni][0]); w[1] = f2bf(acc[mi][ni][1]);
                w[2] = f2bf(acc[mi][ni][2]); w[3] = f2bf(acc[mi][ni][3]);
                *(us4*)&eb[dL * 64 + tchk * 8 + (tokL0 & 7)] = w;
            }
#pragma unroll
        for (int i = 0; i < 8; ++i) {
            int dr = i * 8 + (lane >> 3);
            int ch = lane & 7;
            bf8 v = *(const bf8*)&eb[dr * 64 + ((ch ^ (dr & 7)) << 3)];
            int tok0 = m0 + wr * 64 + ch * 8;
            int bb = tok0 >> 11, nn = tok0 & 2047;
            *(bf8*)&Vo[((bb * 16 + hh) * 64 + dr) * 2048 + nn] = v;
        }
    }
}

// ---------------- vmean: per (b,h) mean of V rows (V^T layout) ----------------
__global__ void vmean_kernel(const u16* __restrict__ VT, float* __restrict__ vmean) {
    int bh = blockIdx.x;
    int tid = threadIdx.x;
    int d = tid >> 2, seg = tid & 3;
    const u16* row = VT + bh * 131072 + d * 2048 + seg * 512;
    float s = 0.f;
    for (int i = 0; i < 512; i += 8) {
        bf8 v = *(const bf8*)&row[i];
#pragma unroll
        for (int j = 0; j < 8; ++j) s += bf2f((u16)v[j]);
    }
    __shared__ float red[256];
    red[tid] = s;
    __syncthreads();
    if (seg == 0)
        vmean[bh * 64 + d] = (red[tid] + red[tid + 1] + red[tid + 2] + red[tid + 3]) * (1.0f / 2048.0f);
}

// ---------------- flash attention (8-warp, 32x32 MFMA, swapped QK^T) ----------------
// grid 256: xcd-swizzled (bh, qtile). 8 warps x 32 q-rows = 256 q/block. KV tile 64.
__global__ __launch_bounds__(512)
void attn_kernel(const u16* __restrict__ Q, const u16* __restrict__ K, const u16* __restrict__ VT,
                 const int* __restrict__ mask, const float* __restrict__ vmean,
                 u16* __restrict__ O)
{
    __shared__ __align__(16) u16 lK[2][4096];
    __shared__ __align__(16) u16 lV[2][4096];
    __shared__ u16 lBias[2048];
    __shared__ __align__(16) u16 lEpi[8][32 * 76];

    const int tid = threadIdx.x;
    const int lane = tid & 63, wid = tid >> 6;
    const int q = lane & 31, hi = lane >> 5;
    const int B = blockIdx.x;
    const int xcd = B & 7, slot = B >> 3;
    const int bh = xcd * 4 + (slot & 3), qt = slot >> 2;
    const int b = bh >> 4, h = bh & 15;
    const u16* Qb = Q + bh * (2048 * 64);
    const u16* Kb = K + bh * (2048 * 64);
    const u16* Vb = VT + bh * (64 * 2048);

    // column bias (mask==0 -> -1e30), token-indexed
    const u16 NEGB = f2bf(-1e30f);
    for (int i = tid; i < 2048; i += 512)
        lBias[i] = mask[b * 2048 + i] ? (u16)0 : NEGB;

    // Q fragments in registers: Q[qrow][16s+8hi .. +8]
    const int qrow = qt * 256 + wid * 32 + q;
    bf8 qf[4];
#pragma unroll
    for (int s = 0; s < 4; ++s)
        qf[s] = *(const bf8*)&Qb[qrow * 64 + s * 16 + hi * 8];

    f16f oacc[2];
#pragma unroll
    for (int i = 0; i < 16; ++i) { oacc[0][i] = 0.f; oacc[1][i] = 0.f; }
    float mrun = -1e30f, lrun = 0.f;

    bf8 oneb;
#pragma unroll
    for (int i = 0; i < 8; ++i) oneb[i] = 0;
    if (hi == 0) oneb[0] = (short)0x3F80;   // bf16 1.0

    // stage tile t into buffer buf: 512 threads x (1 K-chunk + 1 V-chunk)
    const int srow = tid >> 3, scc = tid & 7;
    const int sgc = scc ^ (srow & 7);
    const u16* ksrc0 = Kb + srow * 64 + sgc * 8;
    const u16* vsrc0 = Vb + srow * 2048 + sgc * 8;

    // prologue: stage tile 0
    gld_lds16(ksrc0 + 0 * 64 * 64, &lK[0][tid * 8]);
    gld_lds16(vsrc0 + 0 * 64, &lV[0][tid * 8]);
    __syncthreads();

    for (int t = 0; t < 32; ++t) {
        const int cur = t & 1;
        if (t < 31) {   // prefetch next tile (drains at loop-end barrier, after compute)
            gld_lds16(ksrc0 + (t + 1) * 64 * 64, &lK[cur ^ 1][tid * 8]);
            gld_lds16(vsrc0 + (t + 1) * 64, &lV[cur ^ 1][tid * 8]);
        }
        const u16* kbuf = lK[cur];
        const u16* vbuf = lV[cur];

        // S^T[kv][q] = K Q^T + bias (rank-1 via MFMA)
        f16f st[2];
#pragma unroll
        for (int kb = 0; kb < 2; ++kb) {
            bf8 ba;
#pragma unroll
            for (int i = 0; i < 8; ++i) ba[i] = 0;
            if (hi == 0) ba[0] = (short)lBias[t * 64 + kb * 32 + q];
            f16f z;
#pragma unroll
            for (int i = 0; i < 16; ++i) z[i] = 0.f;
            st[kb] = mfma32(ba, oneb, z);
            const int row = kb * 32 + q;
#pragma unroll
            for (int s = 0; s < 4; ++s) {
                bf8 kf = *(const bf8*)&kbuf[row * 64 + (((2 * s + hi) ^ (row & 7)) << 3)];
                st[kb] = mfma32(kf, qf[s], st[kb]);
            }
        }

        // online softmax: lane owns q-row, 32 kv vals in-lane + partner lane (hi^1)
        float tm = st[0][0];
#pragma unroll
        for (int i = 1; i < 16; ++i) tm = fmaxf(tm, st[0][i]);
#pragma unroll
        for (int i = 0; i < 16; ++i) tm = fmaxf(tm, st[1][i]);
        tm = fmaxf(tm, __shfl_xor(tm, 32));

        if (!__all(tm <= mrun + 8.0f)) {     // T13 defer-max
            float mnew = fmaxf(mrun, tm);
            float al = __expf(mrun - mnew);
            mrun = mnew;
            lrun *= al;
#pragma unroll
            for (int i = 0; i < 16; ++i) { oacc[0][i] *= al; oacc[1][i] *= al; }
        }
        float ts = 0.f;
#pragma unroll
        for (int kb = 0; kb < 2; ++kb)
#pragma unroll
            for (int i = 0; i < 16; ++i) {
                float p = __expf(st[kb][i] - mrun);
                st[kb][i] = p;
                ts += p;
            }
        ts += __shfl_xor(ts, 32);
        lrun += ts;

        // P -> bf16 A-fragments: cvt_pk + permlane32_swap (T12)
        bf8 pa[4];
#pragma unroll
        for (int kb = 0; kb < 2; ++kb)
#pragma unroll
            for (int gp = 0; gp < 2; ++gp) {
                u32 a0 = cvtpk(st[kb][gp * 8 + 0], st[kb][gp * 8 + 1]);
                u32 a1 = cvtpk(st[kb][gp * 8 + 2], st[kb][gp * 8 + 3]);
                u32 b0 = cvtpk(st[kb][gp * 8 + 4], st[kb][gp * 8 + 5]);
                u32 b1 = cvtpk(st[kb][gp * 8 + 6], st[kb][gp * 8 + 7]);
                plswap(a0, b0);
                plswap(a1, b1);
                union { bf8 v; u32 u[4]; } pu;
                pu.u[0] = a0; pu.u[1] = a1; pu.u[2] = b0; pu.u[3] = b1;
                pa[kb * 2 + gp] = pu.v;
            }

        // O[q][d] += P V : mfma(V^T_frag, P_frag) keeps q on lanes
#pragma unroll
        for (int db = 0; db < 2; ++db) {
            const int vrow = db * 32 + q;
#pragma unroll
            for (int s = 0; s < 4; ++s) {
                bf8 vf = *(const bf8*)&vbuf[vrow * 64 + (((2 * s + hi) ^ (vrow & 7)) << 3)];
                oacc[db] = mfma32(vf, pa[s], oacc[db]);
            }
        }
        __syncthreads();   // prefetch drained (covered by compute); readers done before overwrite
    }

    // ---- epilogue: per-warp LDS transpose, vmean override, coalesced stores ----
    const float inv = 1.0f / lrun;
    u16* eb = &lEpi[wid][0];
#pragma unroll
    for (int db = 0; db < 2; ++db)
#pragma unroll
        for (int q2 = 0; q2 < 4; ++q2) {
            us4 w;
            w[0] = f2bf(oacc[db][q2 * 4 + 0] * inv);
            w[1] = f2bf(oacc[db][q2 * 4 + 1] * inv);
            w[2] = f2bf(oacc[db][q2 * 4 + 2] * inv);
            w[3] = f2bf(oacc[db][q2 * 4 + 3] * inv);
            *(us4*)&eb[q * 76 + db * 32 + q2 * 8 + hi * 4] = w;
        }
    // same-warp LDS dependency only; compiler inserts lgkmcnt
#pragma unroll
    for (int i = 0; i < 4; ++i) {
        int row = i * 8 + (lane >> 3);
        int ch = lane & 7;
        bf8 v = *(const bf8*)&eb[row * 76 + ch * 8];
        int tok = qt * 256 + wid * 32 + row;
        if (lBias[tok] != 0) {   // masked query row -> uniform attention = vmean
            const float* vm = vmean + bh * 64 + ch * 8;
            float4 v0 = ((const float4*)vm)[0];
            float4 v1 = ((const float4*)vm)[1];
            v[0] = (short)f2bf(v0.x); v[1] = (short)f2bf(v0.y);
            v[2] = (short)f2bf(v0.z); v[3] = (short)f2bf(v0.w);
            v[4] = (short)f2bf(v1.x); v[5] = (short)f2bf(v1.y);
            v[6] = (short)f2bf(v1.z); v[7] = (short)f2bf(v1.w);
        }
        *(bf8*)&O[(b * 2048 + tok) * 1024 + h * 64 + ch * 8] = v;
    }
}

// ---------------- GEMM2: output projection ----------------
__global__ __launch_bounds__(256)
void gemm_out(const u16* __restrict__ A, const u16* __restrict__ W, float* __restrict__ out)
{
    __shared__ __align__(16) u16 lA[128 * 64];
    __shared__ __align__(16) u16 lB[128 * 64];
    const int tid = threadIdx.x;
    const int lane = tid & 63, wid = tid >> 6;
    const int g = lane >> 4, c = lane & 15;
    const int m0 = blockIdx.y * 128, n0 = blockIdx.x * 128;
    const int wr = wid >> 1, wc = wid & 1;

    f4 acc[4][4];
#pragma unroll
    for (int i = 0; i < 4; ++i)
#pragma unroll
        for (int j = 0; j < 4; ++j) { acc[i][j][0] = 0.f; acc[i][j][1] = 0.f; acc[i][j][2] = 0.f; acc[i][j][3] = 0.f; }

    for (int k0 = 0; k0 < 1024; k0 += 64) {
        __syncthreads();
#pragma unroll
        for (int i = 0; i < 4; ++i) {
            int chunk = i * 256 + tid;
            int row = chunk >> 3, cc = chunk & 7;
            int gc = cc ^ (row & 7);
            gld_lds16(A + (m0 + row) * 1024 + k0 + gc * 8, lA + (i * 256 + wid * 64) * 8);
            gld_lds16(W + (n0 + row) * 1024 + k0 + gc * 8, lB + (i * 256 + wid * 64) * 8);
        }
        __syncthreads();
#pragma unroll
        for (int kk = 0; kk < 2; ++kk) {
            bf8 af[4], bfr[4];
#pragma unroll
            for (int mi = 0; mi < 4; ++mi) {
                int row = wr * 64 + mi * 16 + c;
                af[mi] = *(const bf8*)&lA[row * 64 + ((kk * 4 + g) ^ (row & 7)) * 8];
            }
#pragma unroll
            for (int ni = 0; ni < 4; ++ni) {
                int row = wc * 64 + ni * 16 + c;
                bfr[ni] = *(const bf8*)&lB[row * 64 + ((kk * 4 + g) ^ (row & 7)) * 8];
            }
#pragma unroll
            for (int mi = 0; mi < 4; ++mi)
#pragma unroll
                for (int ni = 0; ni < 4; ++ni)
                    acc[mi][ni] = __builtin_amdgcn_mfma_f32_16x16x32_bf16(af[mi], bfr[ni], acc[mi][ni], 0, 0, 0);
        }
    }
#pragma unroll
    for (int mi = 0; mi < 4; ++mi) {
        int row0 = m0 + wr * 64 + mi * 16 + g * 4;
#pragma unroll
        for (int ni = 0; ni < 4; ++ni) {
            int col = n0 + wc * 64 + ni * 16 + c;
#pragma unroll
            for (int r = 0; r < 4; ++r)
                out[(row0 + r) * 1024 + col] = acc[mi][ni][r];
        }
    }
}

extern "C" void kernel_launch(void* const* d_in, const int* in_sizes, int n_in,
                              void* d_out, int out_size, void* d_ws, size_t ws_size,
                              hipStream_t stream) {
    const float* x    = (const float*)d_in[0];
    const int*   mask = (const int*)d_in[1];
    const float* wqkv = (const float*)d_in[2];
    const float* wout = (const float*)d_in[3];
    float* out = (float*)d_out;

    u16* ws = (u16*)d_ws;
    u16* xbf    = ws;                       // 4096*1024 (reused as attention output)
    u16* wqkvbf = xbf + 4096 * 1024;        // 3072*1024
    u16* woutbf = wqkvbf + 3072 * 1024;     // 1024*1024
    u16* qb     = woutbf + 1024 * 1024;     // [b][h][n][64]
    u16* kb     = qb + 2 * 16 * 2048 * 64;  // [b][h][n][64]
    u16* vtb    = kb + 2 * 16 * 2048 * 64;  // [b][h][64][n]
    float* vmean = (float*)(vtb + 2 * 16 * 2048 * 64);   // 32*64 f32
    u16* ob = xbf;                          // alias: x-bf16 dead after gemm_qkv

    cvt_kernel<<<4096, 256, 0, stream>>>(x, xbf, 4096 * 1024 / 4);
    cvt_kernel<<<3072, 256, 0, stream>>>(wqkv, wqkvbf, 3072 * 1024 / 4);
    cvt_kernel<<<1024, 256, 0, stream>>>(wout, woutbf, 1024 * 1024 / 4);
    gemm_qkv<<<dim3(24, 32), 256, 0, stream>>>(xbf, wqkvbf, qb, kb, vtb);
    vmean_kernel<<<32, 256, 0, stream>>>(vtb, vmean);
    attn_kernel<<<256, 512, 0, stream>>>(qb, kb, vtb, mask, vmean, ob);
    gemm_out<<<dim3(8, 32), 256, 0, stream>>>(ob, woutbf, out);
}